// Round 8
// baseline (16575.426 us; speedup 1.0000x reference)
//
#include <hip/hip_runtime.h>
#include <hip/hip_fp16.h>
#include <math.h>

#define B_ 64
#define T_ 512
#define FSTR 8   // flag stride in ints (32 B) — limits same-cacheline flag contention

// ---------------------------------------------------------------------------
// GEMM: C[M,N] = (A[M,K] * mask[row/T_, :]) @ W[K,N] + bias[N]
// fp32, 64x64 tile, TK=32, 256 threads, 4x4 microtile per thread.
// ---------------------------------------------------------------------------
__global__ __launch_bounds__(256) void gemm_mask_kernel(
    const float* __restrict__ A, const float* __restrict__ W,
    const float* __restrict__ bias, const float* __restrict__ mask,
    float* __restrict__ C, int M, int N, int K)
{
    const int TM = 64, TN = 64, TK = 32;
    __shared__ __align__(16) float As[TK][68];
    __shared__ __align__(16) float Bs[TK][68];

    const int tid = threadIdx.x;
    const int bn = blockIdx.x;
    const int bm = blockIdx.y;
    const int row0 = bm * TM;
    const int b = row0 / T_;

    const int ty = tid >> 4;
    const int tx = tid & 15;
    const int m0 = ty * 4;
    const int n0 = tx * 4;

    float acc[4][4];
#pragma unroll
    for (int i = 0; i < 4; i++)
#pragma unroll
        for (int j = 0; j < 4; j++) acc[i][j] = 0.f;

    for (int kk = 0; kk < K; kk += TK) {
        {
            const int r = tid >> 3;
            const int kq = (tid & 7) << 2;
            const float4 mv = *(const float4*)(mask + (size_t)b * K + kk + kq);
#pragma unroll
            for (int rr = 0; rr < 2; rr++) {
                const int r2 = r + rr * 32;
                const float4 av = *(const float4*)(A + (size_t)(row0 + r2) * K + kk + kq);
                As[kq + 0][r2] = av.x * mv.x;
                As[kq + 1][r2] = av.y * mv.y;
                As[kq + 2][r2] = av.z * mv.z;
                As[kq + 3][r2] = av.w * mv.w;
            }
        }
        {
            const int kr = tid >> 4;
            const int nq = (tid & 15) << 2;
#pragma unroll
            for (int rr = 0; rr < 2; rr++) {
                const int k2 = kr + rr * 16;
                const float4 bv = *(const float4*)(W + (size_t)(kk + k2) * N + bn * TN + nq);
                *(float4*)&Bs[k2][nq] = bv;
            }
        }
        __syncthreads();

#pragma unroll
        for (int k = 0; k < TK; k++) {
            const float4 av = *(const float4*)&As[k][m0];
            const float4 bv = *(const float4*)&Bs[k][n0];
            acc[0][0] += av.x * bv.x; acc[0][1] += av.x * bv.y; acc[0][2] += av.x * bv.z; acc[0][3] += av.x * bv.w;
            acc[1][0] += av.y * bv.x; acc[1][1] += av.y * bv.y; acc[1][2] += av.y * bv.z; acc[1][3] += av.y * bv.w;
            acc[2][0] += av.z * bv.x; acc[2][1] += av.z * bv.y; acc[2][2] += av.z * bv.z; acc[2][3] += av.z * bv.w;
            acc[3][0] += av.w * bv.x; acc[3][1] += av.w * bv.y; acc[3][2] += av.w * bv.z; acc[3][3] += av.w * bv.w;
        }
        __syncthreads();
    }

    const float4 bv = *(const float4*)(bias + bn * TN + n0);
#pragma unroll
    for (int i = 0; i < 4; i++) {
        float4 v;
        v.x = acc[i][0] + bv.x;
        v.y = acc[i][1] + bv.y;
        v.z = acc[i][2] + bv.z;
        v.w = acc[i][3] + bv.w;
        *(float4*)&C[(size_t)(row0 + m0 + i) * N + bn * TN + n0] = v;
    }
}

// ---------------------------------------------------------------------------
// LSTM recurrence v8 = v7 with the LDS layout transposed: UW2[w][c] (column
// fastest). v7's UW[c][w] gave ~16-way bank conflicts (2e8 conflict cycles:
// 64 lanes hit 64 column rows all starting at bank 0; the 4-valued XOR only
// spread them over 16 banks). Now a wave's uint2 reads are stride-2 words =
// 2 lanes/bank = free (m136); h is a wave-uniform uint4 broadcast.
//   F16 path (HN=256): U as half2-over-k words, 128 KB; v_dot2_f32_f16.
//   F32 path (HN=128): U fp32, 64 KB, plain fma.
// 4 blocks/batch (blockIdx = q*64+b), thread (kq,cp) owns gate cols
// {2cp,2cp+1} x k-range. Per step: dot vs LDS U/h, NKG-way LDS reduction,
// activations, cell update, 4-block h exchange via global hbuf + flags
// (relaxed spin + one acquire fence; parity double-buffer).
// ---------------------------------------------------------------------------
typedef _Float16 h2_t __attribute__((ext_vector_type(2)));

__device__ __forceinline__ float fdot2u(unsigned int a, unsigned int b, float c) {
#if __has_builtin(__builtin_amdgcn_fdot2)
    return __builtin_amdgcn_fdot2(__builtin_bit_cast(h2_t, a),
                                  __builtin_bit_cast(h2_t, b), c, false);
#else
    const __half2 ah = __builtin_bit_cast(__half2, a);
    const __half2 bh = __builtin_bit_cast(__half2, b);
    const float2 af = __half22float2(ah), bf = __half22float2(bh);
    return c + af.x * bf.x + af.y * bf.y;
#endif
}
__device__ __forceinline__ unsigned int pack_h2(float x, float y) {
    const __half2 h = __float22half2_rn(make_float2(x, y));
    return __builtin_bit_cast(unsigned int, h);
}
__device__ __forceinline__ float ubits(unsigned int a) { return __builtin_bit_cast(float, a); }

__device__ __forceinline__ float fsig(float z) { return 1.f / (1.f + __expf(-z)); }
__device__ __forceinline__ float ftanh(float z) {
    const float e = __expf(2.f * z);
    return 1.f - 2.f / (e + 1.f);
}

template <int HN, bool F16>
__global__ __launch_bounds__(1024) void lstm_rec_v8(
    const float* __restrict__ xz,   // [B, T, 4*HN]
    const float* __restrict__ U,    // [HN, 4*HN]
    float* __restrict__ hout,       // [B, T, HN] or nullptr
    float* __restrict__ out_last,   // [B, HN] or nullptr
    float* __restrict__ hbuf,       // [2][B_*HN] exchange buffer
    int* __restrict__ flags)        // [B_*4*FSTR], zeroed before launch
{
    constexpr int GATES = 4 * HN;
    constexpr int COLS = HN;            // gate columns per block
    constexpr int CP = COLS / 2;        // column-pairs
    constexpr int NKG = 1024 / CP;      // k-groups
    constexpr int KH = HN / NKG;        // k per thread
    constexpr int HB = HN / 4;          // hidden units per block
    constexpr int KWORDS = F16 ? HN / 2 : HN;   // k-words per column / in h
    constexpr int WPT = F16 ? KH / 2 : KH;      // k-words per thread

    __shared__ __align__(16) unsigned int UW2[KWORDS * COLS];  // [w][c]
    __shared__ __align__(16) unsigned int hW[KWORDS];
    __shared__ __align__(16) float2 zpart[(NKG - 1) * CP];
    __shared__ __align__(16) float act_sh[COLS];

    const int tid = threadIdx.x;
    const int q = blockIdx.x >> 6;      // quarter 0..3
    const int b = blockIdx.x & 63;      // batch element

    const int cp = tid % CP;
    const int kq = tid / CP;            // wave-uniform (CP % 64 == 0)
    const int c0 = 2 * cp;
    const int group = c0 / HB;          // gate 0..3
    const int gcol = group * HN + q * HB + (c0 % HB);
    const int wbase = kq * WPT;

    // ---- one-time: stage U slice into LDS, layout [w][c] ----
    {
        constexpr int NP = 1024 / COLS;
        const int c = tid % COLS;
        const int part = tid / COLS;
        const int gg = c / HB;
        const int gc = gg * HN + q * HB + (c % HB);
        for (int w = part; w < KWORDS; w += NP) {
            unsigned int word;
            if constexpr (F16) {
                const float a = U[(size_t)(2 * w) * GATES + gc];
                const float bb = U[(size_t)(2 * w + 1) * GATES + gc];
                word = pack_h2(a, bb);
            } else {
                word = __builtin_bit_cast(unsigned int, U[(size_t)w * GATES + gc]);
            }
            UW2[w * COLS + c] = word;   // lanes consecutive c -> stride-1, conflict-free
        }
    }
    if (tid < KWORDS) hW[tid] = 0u;     // h_0 = 0 (fp16 0x0000 / fp32 0.0)
    float cst = 0.f;

    const float* xzb = xz + (size_t)b * T_ * GATES + gcol;
    const int fbase = b * 4;
    const bool tanh_gate = (group == 2);

    float2 z0 = make_float2(0.f, 0.f);
    if (kq == 0) z0 = *(const float2*)xzb;   // step-0 xz
    __syncthreads();

#pragma unroll 1
    for (int t = 0; t < T_; ++t) {
        // ---- dot: z[c0,c0+1] over this thread's k-words ----
        float acc0 = 0.f, acc1 = 0.f;
#pragma unroll
        for (int j = 0; j < WPT; j += 4) {
            const int w = wbase + j;
            const uint4 hw4 = *(const uint4*)&hW[w];    // wave-uniform broadcast
            const uint2 u0 = *(const uint2*)&UW2[(w + 0) * COLS + c0];  // stride-2: free
            const uint2 u1 = *(const uint2*)&UW2[(w + 1) * COLS + c0];
            const uint2 u2v = *(const uint2*)&UW2[(w + 2) * COLS + c0];
            const uint2 u3 = *(const uint2*)&UW2[(w + 3) * COLS + c0];
            if constexpr (F16) {
                acc0 = fdot2u(u0.x, hw4.x, acc0); acc1 = fdot2u(u0.y, hw4.x, acc1);
                acc0 = fdot2u(u1.x, hw4.y, acc0); acc1 = fdot2u(u1.y, hw4.y, acc1);
                acc0 = fdot2u(u2v.x, hw4.z, acc0); acc1 = fdot2u(u2v.y, hw4.z, acc1);
                acc0 = fdot2u(u3.x, hw4.w, acc0); acc1 = fdot2u(u3.y, hw4.w, acc1);
            } else {
                acc0 += ubits(u0.x) * ubits(hw4.x); acc1 += ubits(u0.y) * ubits(hw4.x);
                acc0 += ubits(u1.x) * ubits(hw4.y); acc1 += ubits(u1.y) * ubits(hw4.y);
                acc0 += ubits(u2v.x) * ubits(hw4.z); acc1 += ubits(u2v.y) * ubits(hw4.z);
                acc0 += ubits(u3.x) * ubits(hw4.w); acc1 += ubits(u3.y) * ubits(hw4.w);
            }
        }
        if (kq != 0) zpart[(kq - 1) * CP + cp] = make_float2(acc0, acc1);
        __syncthreads();    // bar1

        // ---- reduce + activations (kq==0 threads) ----
        if (kq == 0) {
            float zx = z0.x + acc0;
            float zy = z0.y + acc1;
#pragma unroll
            for (int r = 0; r < NKG - 1; ++r) {
                const float2 p = zpart[r * CP + cp];
                zx += p.x; zy += p.y;
            }
            if (t + 1 < T_) z0 = *(const float2*)(xzb + (size_t)(t + 1) * GATES);  // prefetch
            float ax, ay;
            if (tanh_gate) { ax = ftanh(zx); ay = ftanh(zy); }
            else           { ax = fsig(zx);  ay = fsig(zy);  }
            *(float2*)&act_sh[c0] = make_float2(ax, ay);
        }
        __syncthreads();    // bar2

        // ---- cell update (wave 0, lanes < HB) ----
        float hnew = 0.f;
        if (tid < HB) {
            const float ig = act_sh[tid];
            const float fg = act_sh[HB + tid];
            const float gg = act_sh[2 * HB + tid];
            const float og = act_sh[3 * HB + tid];
            cst = fg * cst + ig * gg;
            hnew = og * ftanh(cst);
            if (hout) hout[((size_t)b * T_ + t) * HN + q * HB + tid] = hnew;
            if (out_last && t == T_ - 1) out_last[(size_t)b * HN + q * HB + tid] = hnew;
        }

        if (t < T_ - 1) {
            const int s = t & 1;
            // publish own h slice (wave 0 lanes)
            if (tid < HB)
                __hip_atomic_store(&hbuf[(size_t)s * B_ * HN + b * HN + q * HB + tid],
                                   hnew, __ATOMIC_RELAXED, __HIP_MEMORY_SCOPE_AGENT);
            if (tid == 0) {
                __threadfence();   // release: covers wave 0's hbuf stores
                __hip_atomic_store(&flags[(fbase + q) * FSTR], t + 1,
                                   __ATOMIC_RELEASE, __HIP_MEMORY_SCOPE_AGENT);
            }
            // relaxed spin (lanes 0..3), then ONE acquire fence for the wave
            if (tid < 4) {
                while (__hip_atomic_load(&flags[(fbase + tid) * FSTR],
                                         __ATOMIC_RELAXED, __HIP_MEMORY_SCOPE_AGENT) < t + 1) {}
            }
            if (tid < 64) {
                __threadfence();   // acquire: order pull loads after observed flags
                if constexpr (F16) {
                    const float4 hv = *(const float4*)&hbuf[(size_t)s * B_ * HN + b * HN + 4 * tid];
                    unsigned int w0 = pack_h2(hv.x, hv.y);
                    unsigned int w1 = pack_h2(hv.z, hv.w);
                    *(uint2*)&hW[2 * tid] = make_uint2(w0, w1);
                } else {
                    if (tid < HN / 4) {
                        const float4 hv = *(const float4*)&hbuf[(size_t)s * B_ * HN + b * HN + 4 * tid];
                        uint4 wv;
                        wv.x = __builtin_bit_cast(unsigned int, hv.x);
                        wv.y = __builtin_bit_cast(unsigned int, hv.y);
                        wv.z = __builtin_bit_cast(unsigned int, hv.z);
                        wv.w = __builtin_bit_cast(unsigned int, hv.w);
                        *(uint4*)&hW[4 * tid] = wv;
                    }
                }
            }
            __syncthreads();    // bar3
        }
    }
}

// ---------------------------------------------------------------------------
// Launch
// ---------------------------------------------------------------------------
extern "C" void kernel_launch(void* const* d_in, const int* in_sizes, int n_in,
                              void* d_out, int out_size, void* d_ws, size_t ws_size,
                              hipStream_t stream)
{
    const float* x  = (const float*)d_in[0];
    const float* W0 = (const float*)d_in[1];
    const float* U0 = (const float*)d_in[2];
    const float* b0 = (const float*)d_in[3];
    const float* W1 = (const float*)d_in[4];
    const float* U1 = (const float*)d_in[5];
    const float* b1 = (const float*)d_in[6];
    const float* W2 = (const float*)d_in[7];
    const float* U2 = (const float*)d_in[8];
    const float* b2 = (const float*)d_in[9];
    const float* m0 = (const float*)d_in[10];
    const float* m1 = (const float*)d_in[11];
    const float* m2 = (const float*)d_in[12];
    float* out = (float*)d_out;

    // workspace layout (fp32):
    //   xz    : 134217728 B   (64*512*1024 floats, reused by all 3 layers)
    //   h0    :  33554432 B
    //   h1    :  33554432 B
    //   hbuf  :    131072 B   (2 x 64 x 256 floats, shared across layers)
    //   flags :  3 layers x 64*4*FSTR ints = 24576 B
    char* ws = (char*)d_ws;
    float* xz   = (float*)ws;
    float* h0   = (float*)(ws + 134217728);
    float* h1   = (float*)(ws + 134217728 + 33554432);
    float* hbuf = (float*)(ws + 134217728 + 2 * 33554432);
    int*   flg  = (int*)  (ws + 134217728 + 2 * 33554432 + 131072);

    // flags must start at 0 every call (d_ws is poisoned 0xAA)
    hipMemsetAsync(flg, 0, 3 * B_ * 4 * FSTR * sizeof(int), stream);

    const int M = B_ * T_;  // 32768
    const int FL = B_ * 4 * FSTR;

    // Layer 0
    gemm_mask_kernel<<<dim3(1024 / 64, M / 64), 256, 0, stream>>>(x, W0, b0, m0, xz, M, 1024, 128);
    lstm_rec_v8<256, true><<<256, 1024, 0, stream>>>(xz, U0, h0, nullptr, hbuf, flg);

    // Layer 1
    gemm_mask_kernel<<<dim3(1024 / 64, M / 64), 256, 0, stream>>>(h0, W1, b1, m1, xz, M, 1024, 256);
    lstm_rec_v8<256, true><<<256, 1024, 0, stream>>>(xz, U1, h1, nullptr, hbuf, flg + FL);

    // Layer 2 (H=128, fp32 LDS), emit last h only
    gemm_mask_kernel<<<dim3(512 / 64, M / 64), 256, 0, stream>>>(h1, W2, b2, m2, xz, M, 512, 256);
    lstm_rec_v8<128, false><<<256, 1024, 0, stream>>>(xz, U2, nullptr, out, hbuf, flg + 2 * FL);
}

// Round 9
// 3897.419 us; speedup vs baseline: 4.2529x; 4.2529x over previous
//
#include <hip/hip_runtime.h>
#include <hip/hip_fp16.h>
#include <math.h>

#define B_ 64
#define T_ 512
#define FSTR 8   // flag stride in ints (32 B)

// ---------------------------------------------------------------------------
// GEMM: C[M,N] = (A[M,K] * mask[row/T_, :]) @ W[K,N] + bias[N]
// fp32, 64x64 tile, TK=32, 256 threads, 4x4 microtile per thread.
// ---------------------------------------------------------------------------
__global__ __launch_bounds__(256) void gemm_mask_kernel(
    const float* __restrict__ A, const float* __restrict__ W,
    const float* __restrict__ bias, const float* __restrict__ mask,
    float* __restrict__ C, int M, int N, int K)
{
    const int TM = 64, TN = 64, TK = 32;
    __shared__ __align__(16) float As[TK][68];
    __shared__ __align__(16) float Bs[TK][68];

    const int tid = threadIdx.x;
    const int bn = blockIdx.x;
    const int bm = blockIdx.y;
    const int row0 = bm * TM;
    const int b = row0 / T_;

    const int ty = tid >> 4;
    const int tx = tid & 15;
    const int m0 = ty * 4;
    const int n0 = tx * 4;

    float acc[4][4];
#pragma unroll
    for (int i = 0; i < 4; i++)
#pragma unroll
        for (int j = 0; j < 4; j++) acc[i][j] = 0.f;

    for (int kk = 0; kk < K; kk += TK) {
        {
            const int r = tid >> 3;
            const int kq = (tid & 7) << 2;
            const float4 mv = *(const float4*)(mask + (size_t)b * K + kk + kq);
#pragma unroll
            for (int rr = 0; rr < 2; rr++) {
                const int r2 = r + rr * 32;
                const float4 av = *(const float4*)(A + (size_t)(row0 + r2) * K + kk + kq);
                As[kq + 0][r2] = av.x * mv.x;
                As[kq + 1][r2] = av.y * mv.y;
                As[kq + 2][r2] = av.z * mv.z;
                As[kq + 3][r2] = av.w * mv.w;
            }
        }
        {
            const int kr = tid >> 4;
            const int nq = (tid & 15) << 2;
#pragma unroll
            for (int rr = 0; rr < 2; rr++) {
                const int k2 = kr + rr * 16;
                const float4 bv = *(const float4*)(W + (size_t)(kk + k2) * N + bn * TN + nq);
                *(float4*)&Bs[k2][nq] = bv;
            }
        }
        __syncthreads();

#pragma unroll
        for (int k = 0; k < TK; k++) {
            const float4 av = *(const float4*)&As[k][m0];
            const float4 bv = *(const float4*)&Bs[k][n0];
            acc[0][0] += av.x * bv.x; acc[0][1] += av.x * bv.y; acc[0][2] += av.x * bv.z; acc[0][3] += av.x * bv.w;
            acc[1][0] += av.y * bv.x; acc[1][1] += av.y * bv.y; acc[1][2] += av.y * bv.z; acc[1][3] += av.y * bv.w;
            acc[2][0] += av.z * bv.x; acc[2][1] += av.z * bv.y; acc[2][2] += av.z * bv.z; acc[2][3] += av.z * bv.w;
            acc[3][0] += av.w * bv.x; acc[3][1] += av.w * bv.y; acc[3][2] += av.w * bv.z; acc[3][3] += av.w * bv.w;
        }
        __syncthreads();
    }

    const float4 bv = *(const float4*)(bias + bn * TN + n0);
#pragma unroll
    for (int i = 0; i < 4; i++) {
        float4 v;
        v.x = acc[i][0] + bv.x;
        v.y = acc[i][1] + bv.y;
        v.z = acc[i][2] + bv.z;
        v.w = acc[i][3] + bv.w;
        *(float4*)&C[(size_t)(row0 + m0 + i) * N + bn * TN + n0] = v;
    }
}

// ---------------------------------------------------------------------------
// LSTM recurrence v9 = v8 minus the agent-scope fences (the r8 post-mortem
// bottleneck: per-step buffer_wbl2 / buffer_inv L2 flushes).
// All cross-block data (h exchange + flags) moves via RELAXED AGENT atomics
// (per-access write-through/bypass to the coherence point — no cache flush).
// Publisher ordering: h atomic stores -> s_waitcnt vmcnt(0) -> flag store.
// Consumer ordering: spin on flags (relaxed) -> in-order issue of h atomic
// loads (64-bit, coalesced) -> LDS -> barrier.
// Role split so wave 0's vmcnt(0) waits ONLY its h-stores: reduce +
// activations + xz prefetch moved to the LAST k-group (waves 14/15); hout
// store issued after the flag store (off critical path).
// LDS layout unchanged from v8 (UW2[w][c], conflict-free, 0 conflicts in r8).
// ---------------------------------------------------------------------------
typedef _Float16 h2_t __attribute__((ext_vector_type(2)));

__device__ __forceinline__ float fdot2u(unsigned int a, unsigned int b, float c) {
#if __has_builtin(__builtin_amdgcn_fdot2)
    return __builtin_amdgcn_fdot2(__builtin_bit_cast(h2_t, a),
                                  __builtin_bit_cast(h2_t, b), c, false);
#else
    const __half2 ah = __builtin_bit_cast(__half2, a);
    const __half2 bh = __builtin_bit_cast(__half2, b);
    const float2 af = __half22float2(ah), bf = __half22float2(bh);
    return c + af.x * bf.x + af.y * bf.y;
#endif
}
__device__ __forceinline__ unsigned int pack_h2(float x, float y) {
    const __half2 h = __float22half2_rn(make_float2(x, y));
    return __builtin_bit_cast(unsigned int, h);
}
__device__ __forceinline__ float ubits(unsigned int a) { return __builtin_bit_cast(float, a); }
__device__ __forceinline__ float qlo(unsigned long long v) {
    return __builtin_bit_cast(float, (unsigned int)v);
}
__device__ __forceinline__ float qhi(unsigned long long v) {
    return __builtin_bit_cast(float, (unsigned int)(v >> 32));
}

__device__ __forceinline__ float fsig(float z) { return 1.f / (1.f + __expf(-z)); }
__device__ __forceinline__ float ftanh(float z) {
    const float e = __expf(2.f * z);
    return 1.f - 2.f / (e + 1.f);
}

template <int HN, bool F16>
__global__ __launch_bounds__(1024) void lstm_rec_v9(
    const float* __restrict__ xz,   // [B, T, 4*HN]
    const float* __restrict__ U,    // [HN, 4*HN]
    float* __restrict__ hout,       // [B, T, HN] or nullptr
    float* __restrict__ out_last,   // [B, HN] or nullptr
    float* __restrict__ hbuf,       // [2][B_*HN] exchange buffer
    int* __restrict__ flags)        // [B_*4*FSTR], zeroed before launch
{
    constexpr int GATES = 4 * HN;
    constexpr int COLS = HN;            // gate columns per block
    constexpr int CP = COLS / 2;        // column-pairs
    constexpr int NKG = 1024 / CP;      // k-groups
    constexpr int KH = HN / NKG;        // k per thread
    constexpr int HB = HN / 4;          // hidden units per block
    constexpr int KWORDS = F16 ? HN / 2 : HN;
    constexpr int WPT = F16 ? KH / 2 : KH;

    __shared__ __align__(16) unsigned int UW2[KWORDS * COLS];  // [w][c]
    __shared__ __align__(16) unsigned int hW[KWORDS];
    __shared__ __align__(16) float2 zpart[(NKG - 1) * CP];
    __shared__ __align__(16) float act_sh[COLS];

    const int tid = threadIdx.x;
    const int q = blockIdx.x >> 6;      // quarter 0..3
    const int b = blockIdx.x & 63;      // batch element

    const int cp = tid % CP;
    const int kq = tid / CP;            // wave-uniform (CP % 64 == 0)
    const int c0 = 2 * cp;
    const int group = c0 / HB;          // gate 0..3
    const int gcol = group * HN + q * HB + (c0 % HB);
    const int wbase = kq * WPT;
    const bool red_grp = (kq == NKG - 1);   // reduce/act/prefetch role

    // ---- one-time: stage U slice into LDS, layout [w][c] ----
    {
        constexpr int NP = 1024 / COLS;
        const int c = tid % COLS;
        const int part = tid / COLS;
        const int gg = c / HB;
        const int gc = gg * HN + q * HB + (c % HB);
        for (int w = part; w < KWORDS; w += NP) {
            unsigned int word;
            if constexpr (F16) {
                const float a = U[(size_t)(2 * w) * GATES + gc];
                const float bb = U[(size_t)(2 * w + 1) * GATES + gc];
                word = pack_h2(a, bb);
            } else {
                word = __builtin_bit_cast(unsigned int, U[(size_t)w * GATES + gc]);
            }
            UW2[w * COLS + c] = word;
        }
    }
    if (tid < KWORDS) hW[tid] = 0u;     // h_0 = 0
    float cst = 0.f;

    const float* xzb = xz + (size_t)b * T_ * GATES + gcol;
    const int fbase = b * 4;
    const bool tanh_gate = (group == 2);

    float2 z0 = make_float2(0.f, 0.f);
    if (red_grp) z0 = *(const float2*)xzb;   // step-0 xz
    __syncthreads();

#pragma unroll 1
    for (int t = 0; t < T_; ++t) {
        // ---- dot: z[c0,c0+1] over this thread's k-words (LDS only) ----
        float acc0 = 0.f, acc1 = 0.f;
#pragma unroll
        for (int j = 0; j < WPT; j += 4) {
            const int w = wbase + j;
            const uint4 hw4 = *(const uint4*)&hW[w];    // wave-uniform broadcast
            const uint2 u0 = *(const uint2*)&UW2[(w + 0) * COLS + c0];
            const uint2 u1 = *(const uint2*)&UW2[(w + 1) * COLS + c0];
            const uint2 u2v = *(const uint2*)&UW2[(w + 2) * COLS + c0];
            const uint2 u3 = *(const uint2*)&UW2[(w + 3) * COLS + c0];
            if constexpr (F16) {
                acc0 = fdot2u(u0.x, hw4.x, acc0); acc1 = fdot2u(u0.y, hw4.x, acc1);
                acc0 = fdot2u(u1.x, hw4.y, acc0); acc1 = fdot2u(u1.y, hw4.y, acc1);
                acc0 = fdot2u(u2v.x, hw4.z, acc0); acc1 = fdot2u(u2v.y, hw4.z, acc1);
                acc0 = fdot2u(u3.x, hw4.w, acc0); acc1 = fdot2u(u3.y, hw4.w, acc1);
            } else {
                acc0 += ubits(u0.x) * ubits(hw4.x); acc1 += ubits(u0.y) * ubits(hw4.x);
                acc0 += ubits(u1.x) * ubits(hw4.y); acc1 += ubits(u1.y) * ubits(hw4.y);
                acc0 += ubits(u2v.x) * ubits(hw4.z); acc1 += ubits(u2v.y) * ubits(hw4.z);
                acc0 += ubits(u3.x) * ubits(hw4.w); acc1 += ubits(u3.y) * ubits(hw4.w);
            }
        }
        if (!red_grp) zpart[kq * CP + cp] = make_float2(acc0, acc1);
        __syncthreads();    // bar1

        // ---- reduce + activations + xz prefetch (LAST k-group: waves 14/15) ----
        if (red_grp) {
            float zx = z0.x + acc0;
            float zy = z0.y + acc1;
#pragma unroll
            for (int r = 0; r < NKG - 1; ++r) {
                const float2 p = zpart[r * CP + cp];
                zx += p.x; zy += p.y;
            }
            if (t + 1 < T_) z0 = *(const float2*)(xzb + (size_t)(t + 1) * GATES);  // prefetch
            float ax, ay;
            if (tanh_gate) { ax = ftanh(zx); ay = ftanh(zy); }
            else           { ax = fsig(zx);  ay = fsig(zy);  }
            *(float2*)&act_sh[c0] = make_float2(ax, ay);
        }
        __syncthreads();    // bar2

        // ---- cell update (wave 0, lanes < HB) ----
        float hnew = 0.f;
        if (tid < HB) {
            const float ig = act_sh[tid];
            const float fg = act_sh[HB + tid];
            const float gg = act_sh[2 * HB + tid];
            const float og = act_sh[3 * HB + tid];
            cst = fg * cst + ig * gg;
            hnew = og * ftanh(cst);
            if (out_last && t == T_ - 1) out_last[(size_t)b * HN + q * HB + tid] = hnew;
        }

        if (t < T_ - 1) {
            const int s = t & 1;
            float* hslot = hbuf + (size_t)s * B_ * HN + b * HN;

            // publish own h slice: relaxed AGENT atomics (write-through, no fence)
            if (tid < HB)
                __hip_atomic_store(&hslot[q * HB + tid], hnew,
                                   __ATOMIC_RELAXED, __HIP_MEMORY_SCOPE_AGENT);
            if (tid < 64) {
                // wave 0 only: its sole outstanding vmem ops are the h stores
                asm volatile("s_waitcnt vmcnt(0)" ::: "memory");
            }
            if (tid == 0)
                __hip_atomic_store(&flags[(fbase + q) * FSTR], t + 1,
                                   __ATOMIC_RELAXED, __HIP_MEMORY_SCOPE_AGENT);

            // hout store AFTER the flag (off critical path, cached)
            if (hout && tid < HB)
                hout[((size_t)b * T_ + t) * HN + q * HB + tid] = hnew;

            // spin on all 4 sibling flags (lanes 0..3 of wave 0), relaxed
            if (tid < 4) {
                while (__hip_atomic_load(&flags[(fbase + tid) * FSTR],
                                         __ATOMIC_RELAXED, __HIP_MEMORY_SCOPE_AGENT) < t + 1) {}
            }
            asm volatile("" ::: "memory");   // compiler barrier: loads below stay below

            // pull full h (relaxed AGENT 64-bit atomic loads, coalesced) -> LDS
            if (tid < 64) {
                const unsigned long long* hq =
                    (const unsigned long long*)hslot;
                if constexpr (F16) {
                    // 128 qwords: lanes i -> qwords i and i+64
                    const unsigned long long v0 = __hip_atomic_load(&hq[tid],
                        __ATOMIC_RELAXED, __HIP_MEMORY_SCOPE_AGENT);
                    const unsigned long long v1 = __hip_atomic_load(&hq[tid + 64],
                        __ATOMIC_RELAXED, __HIP_MEMORY_SCOPE_AGENT);
                    hW[tid]      = pack_h2(qlo(v0), qhi(v0));
                    hW[tid + 64] = pack_h2(qlo(v1), qhi(v1));
                } else {
                    // 64 qwords: lane i -> qword i -> hW[2i],hW[2i+1]
                    const unsigned long long v0 = __hip_atomic_load(&hq[tid],
                        __ATOMIC_RELAXED, __HIP_MEMORY_SCOPE_AGENT);
                    uint2 wv;
                    wv.x = (unsigned int)v0;
                    wv.y = (unsigned int)(v0 >> 32);
                    *(uint2*)&hW[2 * tid] = wv;
                }
            }
            __syncthreads();    // bar3
        } else if (hout && tid < HB) {
            hout[((size_t)b * T_ + t) * HN + q * HB + tid] = hnew;
        }
    }
}

// ---------------------------------------------------------------------------
// Launch
// ---------------------------------------------------------------------------
extern "C" void kernel_launch(void* const* d_in, const int* in_sizes, int n_in,
                              void* d_out, int out_size, void* d_ws, size_t ws_size,
                              hipStream_t stream)
{
    const float* x  = (const float*)d_in[0];
    const float* W0 = (const float*)d_in[1];
    const float* U0 = (const float*)d_in[2];
    const float* b0 = (const float*)d_in[3];
    const float* W1 = (const float*)d_in[4];
    const float* U1 = (const float*)d_in[5];
    const float* b1 = (const float*)d_in[6];
    const float* W2 = (const float*)d_in[7];
    const float* U2 = (const float*)d_in[8];
    const float* b2 = (const float*)d_in[9];
    const float* m0 = (const float*)d_in[10];
    const float* m1 = (const float*)d_in[11];
    const float* m2 = (const float*)d_in[12];
    float* out = (float*)d_out;

    // workspace layout (fp32):
    //   xz    : 134217728 B   (64*512*1024 floats, reused by all 3 layers)
    //   h0    :  33554432 B
    //   h1    :  33554432 B
    //   hbuf  :    131072 B   (2 x 64 x 256 floats, shared across layers)
    //   flags :  3 layers x 64*4*FSTR ints = 24576 B
    char* ws = (char*)d_ws;
    float* xz   = (float*)ws;
    float* h0   = (float*)(ws + 134217728);
    float* h1   = (float*)(ws + 134217728 + 33554432);
    float* hbuf = (float*)(ws + 134217728 + 2 * 33554432);
    int*   flg  = (int*)  (ws + 134217728 + 2 * 33554432 + 131072);

    // flags must start at 0 every call (d_ws is poisoned 0xAA)
    hipMemsetAsync(flg, 0, 3 * B_ * 4 * FSTR * sizeof(int), stream);

    const int M = B_ * T_;  // 32768
    const int FL = B_ * 4 * FSTR;

    // Layer 0
    gemm_mask_kernel<<<dim3(1024 / 64, M / 64), 256, 0, stream>>>(x, W0, b0, m0, xz, M, 1024, 128);
    lstm_rec_v9<256, true><<<256, 1024, 0, stream>>>(xz, U0, h0, nullptr, hbuf, flg);

    // Layer 1
    gemm_mask_kernel<<<dim3(1024 / 64, M / 64), 256, 0, stream>>>(h0, W1, b1, m1, xz, M, 1024, 256);
    lstm_rec_v9<256, true><<<256, 1024, 0, stream>>>(xz, U1, h1, nullptr, hbuf, flg + FL);

    // Layer 2 (H=128, fp32 LDS), emit last h only
    gemm_mask_kernel<<<dim3(512 / 64, M / 64), 256, 0, stream>>>(h1, W2, b2, m2, xz, M, 512, 256);
    lstm_rec_v9<128, false><<<256, 1024, 0, stream>>>(xz, U2, nullptr, out, hbuf, flg + 2 * FL);
}

// Round 10
// 3109.418 us; speedup vs baseline: 5.3307x; 1.2534x over previous
//
#include <hip/hip_runtime.h>
#include <hip/hip_fp16.h>
#include <math.h>

#define B_ 64
#define T_ 512

typedef _Float16 h2_t __attribute__((ext_vector_type(2)));

__device__ __forceinline__ float fdot2u(unsigned int a, unsigned int b, float c) {
#if __has_builtin(__builtin_amdgcn_fdot2)
    return __builtin_amdgcn_fdot2(__builtin_bit_cast(h2_t, a),
                                  __builtin_bit_cast(h2_t, b), c, false);
#else
    const __half2 ah = __builtin_bit_cast(__half2, a);
    const __half2 bh = __builtin_bit_cast(__half2, b);
    const float2 af = __half22float2(ah), bf = __half22float2(bh);
    return c + af.x * bf.x + af.y * bf.y;
#endif
}
__device__ __forceinline__ unsigned int pack_h2(float x, float y) {
    const __half2 h = __float22half2_rn(make_float2(x, y));
    return __builtin_bit_cast(unsigned int, h);
}
__device__ __forceinline__ float ubits(unsigned int a) { return __builtin_bit_cast(float, a); }
__device__ __forceinline__ unsigned short f2h_bits(float x) {
    return __builtin_bit_cast(unsigned short, (_Float16)x);
}
__device__ __forceinline__ float h2f_bits(unsigned int bits) {
    return (float)__builtin_bit_cast(_Float16, (unsigned short)(bits & 0xffffu));
}

__device__ __forceinline__ float fsig(float z) { return 1.f / (1.f + __expf(-z)); }
__device__ __forceinline__ float ftanh(float z) {
    const float e = __expf(2.f * z);
    return 1.f - 2.f / (e + 1.f);
}

// ---------------------------------------------------------------------------
// GEMM v2: C[M,N] = (A[M,K]*mask)@W[K,N] + bias, packed-fp16 dot2 inner loop.
// 64x64 tile, TK=32 (16 k-pairs), 256 threads, 4x4 microtile.
// LDS words are half2 over k: As2[kp][m] = (A[m][2kp],A[m][2kp+1])*mask,
// Bs2[kp][n] = (W[2kp][n],W[2kp+1][n]). 16 dot2 + 2 b128 reads per k-pair
// (vs 32 fma + 4 b128 for fp32): ~2x fewer VALU ops and LDS traffic.
// ---------------------------------------------------------------------------
__global__ __launch_bounds__(256) void gemm_mask_f16(
    const float* __restrict__ A, const float* __restrict__ W,
    const float* __restrict__ bias, const float* __restrict__ mask,
    float* __restrict__ C, int M, int N, int K)
{
    const int TM = 64, TN = 64, TK = 32, KP = 16;
    __shared__ __align__(16) unsigned int As2[KP][68];
    __shared__ __align__(16) unsigned int Bs2[KP][68];

    const int tid = threadIdx.x;
    const int bn = blockIdx.x;
    const int bm = blockIdx.y;
    const int row0 = bm * TM;
    const int b = row0 / T_;

    const int ty = tid >> 4;
    const int tx = tid & 15;
    const int m0 = ty * 4;
    const int n0 = tx * 4;

    float acc[4][4];
#pragma unroll
    for (int i = 0; i < 4; i++)
#pragma unroll
        for (int j = 0; j < 4; j++) acc[i][j] = 0.f;

    for (int kk = 0; kk < K; kk += TK) {
        // stage A: thread (m = tid>>2, kq = (tid&3)*8) covers 8 k -> 4 words
        {
            const int m = tid >> 2;
            const int kq = (tid & 3) * 8;
            const float4 mv0 = *(const float4*)(mask + (size_t)b * K + kk + kq);
            const float4 mv1 = *(const float4*)(mask + (size_t)b * K + kk + kq + 4);
            const float4 a0 = *(const float4*)(A + (size_t)(row0 + m) * K + kk + kq);
            const float4 a1 = *(const float4*)(A + (size_t)(row0 + m) * K + kk + kq + 4);
            As2[kq / 2 + 0][m] = pack_h2(a0.x * mv0.x, a0.y * mv0.y);
            As2[kq / 2 + 1][m] = pack_h2(a0.z * mv0.z, a0.w * mv0.w);
            As2[kq / 2 + 2][m] = pack_h2(a1.x * mv1.x, a1.y * mv1.y);
            As2[kq / 2 + 3][m] = pack_h2(a1.z * mv1.z, a1.w * mv1.w);
        }
        // stage B: thread (kp = tid>>4, nq = (tid&15)*4)
        {
            const int kp = tid >> 4;
            const int nq = (tid & 15) * 4;
            const float4 w0 = *(const float4*)(W + (size_t)(kk + 2 * kp) * N + bn * TN + nq);
            const float4 w1 = *(const float4*)(W + (size_t)(kk + 2 * kp + 1) * N + bn * TN + nq);
            uint4 pv;
            pv.x = pack_h2(w0.x, w1.x);
            pv.y = pack_h2(w0.y, w1.y);
            pv.z = pack_h2(w0.z, w1.z);
            pv.w = pack_h2(w0.w, w1.w);
            *(uint4*)&Bs2[kp][nq] = pv;
        }
        __syncthreads();

#pragma unroll
        for (int kp = 0; kp < KP; kp++) {
            const uint4 a4 = *(const uint4*)&As2[kp][m0];
            const uint4 b4 = *(const uint4*)&Bs2[kp][n0];
            acc[0][0] = fdot2u(a4.x, b4.x, acc[0][0]); acc[0][1] = fdot2u(a4.x, b4.y, acc[0][1]);
            acc[0][2] = fdot2u(a4.x, b4.z, acc[0][2]); acc[0][3] = fdot2u(a4.x, b4.w, acc[0][3]);
            acc[1][0] = fdot2u(a4.y, b4.x, acc[1][0]); acc[1][1] = fdot2u(a4.y, b4.y, acc[1][1]);
            acc[1][2] = fdot2u(a4.y, b4.z, acc[1][2]); acc[1][3] = fdot2u(a4.y, b4.w, acc[1][3]);
            acc[2][0] = fdot2u(a4.z, b4.x, acc[2][0]); acc[2][1] = fdot2u(a4.z, b4.y, acc[2][1]);
            acc[2][2] = fdot2u(a4.z, b4.z, acc[2][2]); acc[2][3] = fdot2u(a4.z, b4.w, acc[2][3]);
            acc[3][0] = fdot2u(a4.w, b4.x, acc[3][0]); acc[3][1] = fdot2u(a4.w, b4.y, acc[3][1]);
            acc[3][2] = fdot2u(a4.w, b4.z, acc[3][2]); acc[3][3] = fdot2u(a4.w, b4.w, acc[3][3]);
        }
        __syncthreads();
    }

    const float4 bv = *(const float4*)(bias + bn * TN + n0);
#pragma unroll
    for (int i = 0; i < 4; i++) {
        float4 v;
        v.x = acc[i][0] + bv.x;
        v.y = acc[i][1] + bv.y;
        v.z = acc[i][2] + bv.z;
        v.w = acc[i][3] + bv.w;
        *(float4*)&C[(size_t)(row0 + m0 + i) * N + bn * TN + n0] = v;
    }
}

// ---------------------------------------------------------------------------
// LSTM recurrence v10 = v9 with the flag protocol replaced by TAGGED DATA.
// Published word = {tag = t+1 (hi16), fp16 h (lo16)}: 32-bit atomicity makes
// data+tag inseparable -> consumer loads + retries until tag == t+1. This
// removes the publisher's s_waitcnt vmcnt(0), the flag store, and the poll
// round-trip: ONE L3 round-trip per step instead of three (r9 critical path).
// Parity double-buffer bounds skew to 1 step (a sibling needs my tag-(t+2)
// data before it can write tag t+3 into this slot), so a slot holds tag t+1
// (fresh) or <= t-1 (stale) -- never a future tag. Per-layer hbuf regions
// avoid cross-dispatch tag collisions; ws 0xAA poison (tag 0xAAAA) never
// matches tags <= 512. Everything else identical to v9 (0 bank conflicts).
// ---------------------------------------------------------------------------
template <int HN, bool F16>
__global__ __launch_bounds__(1024) void lstm_rec_v10(
    const float* __restrict__ xz,       // [B, T, 4*HN]
    const float* __restrict__ U,        // [HN, 4*HN]
    float* __restrict__ hout,           // [B, T, HN] or nullptr
    float* __restrict__ out_last,       // [B, HN] or nullptr
    unsigned int* __restrict__ hbuf)    // [2][B_*HN] tagged words
{
    constexpr int GATES = 4 * HN;
    constexpr int COLS = HN;
    constexpr int CP = COLS / 2;
    constexpr int NKG = 1024 / CP;
    constexpr int KH = HN / NKG;
    constexpr int HB = HN / 4;
    constexpr int KWORDS = F16 ? HN / 2 : HN;
    constexpr int WPT = F16 ? KH / 2 : KH;

    __shared__ __align__(16) unsigned int UW2[KWORDS * COLS];  // [w][c]
    __shared__ __align__(16) unsigned int hW[KWORDS];
    __shared__ __align__(16) float2 zpart[(NKG - 1) * CP];
    __shared__ __align__(16) float act_sh[COLS];

    const int tid = threadIdx.x;
    const int q = blockIdx.x >> 6;      // quarter 0..3
    const int b = blockIdx.x & 63;      // batch element (siblings share an XCD)

    const int cp = tid % CP;
    const int kq = tid / CP;            // wave-uniform (CP % 64 == 0)
    const int c0 = 2 * cp;
    const int group = c0 / HB;
    const int gcol = group * HN + q * HB + (c0 % HB);
    const int wbase = kq * WPT;
    const bool red_grp = (kq == NKG - 1);

    // ---- one-time: stage U slice into LDS, layout [w][c] ----
    {
        constexpr int NP = 1024 / COLS;
        const int c = tid % COLS;
        const int part = tid / COLS;
        const int gg = c / HB;
        const int gc = gg * HN + q * HB + (c % HB);
        for (int w = part; w < KWORDS; w += NP) {
            unsigned int word;
            if constexpr (F16) {
                const float a = U[(size_t)(2 * w) * GATES + gc];
                const float bb = U[(size_t)(2 * w + 1) * GATES + gc];
                word = pack_h2(a, bb);
            } else {
                word = __builtin_bit_cast(unsigned int, U[(size_t)w * GATES + gc]);
            }
            UW2[w * COLS + c] = word;
        }
    }
    if (tid < KWORDS) hW[tid] = 0u;     // h_0 = 0
    float cst = 0.f;

    const float* xzb = xz + (size_t)b * T_ * GATES + gcol;
    const bool tanh_gate = (group == 2);

    float2 z0 = make_float2(0.f, 0.f);
    if (red_grp) z0 = *(const float2*)xzb;   // step-0 xz
    __syncthreads();

#pragma unroll 1
    for (int t = 0; t < T_; ++t) {
        // ---- dot: z[c0,c0+1] over this thread's k-words (LDS only) ----
        float acc0 = 0.f, acc1 = 0.f;
#pragma unroll
        for (int j = 0; j < WPT; j += 4) {
            const int w = wbase + j;
            const uint4 hw4 = *(const uint4*)&hW[w];    // wave-uniform broadcast
            const uint2 u0 = *(const uint2*)&UW2[(w + 0) * COLS + c0];
            const uint2 u1 = *(const uint2*)&UW2[(w + 1) * COLS + c0];
            const uint2 u2v = *(const uint2*)&UW2[(w + 2) * COLS + c0];
            const uint2 u3 = *(const uint2*)&UW2[(w + 3) * COLS + c0];
            if constexpr (F16) {
                acc0 = fdot2u(u0.x, hw4.x, acc0); acc1 = fdot2u(u0.y, hw4.x, acc1);
                acc0 = fdot2u(u1.x, hw4.y, acc0); acc1 = fdot2u(u1.y, hw4.y, acc1);
                acc0 = fdot2u(u2v.x, hw4.z, acc0); acc1 = fdot2u(u2v.y, hw4.z, acc1);
                acc0 = fdot2u(u3.x, hw4.w, acc0); acc1 = fdot2u(u3.y, hw4.w, acc1);
            } else {
                acc0 += ubits(u0.x) * ubits(hw4.x); acc1 += ubits(u0.y) * ubits(hw4.x);
                acc0 += ubits(u1.x) * ubits(hw4.y); acc1 += ubits(u1.y) * ubits(hw4.y);
                acc0 += ubits(u2v.x) * ubits(hw4.z); acc1 += ubits(u2v.y) * ubits(hw4.z);
                acc0 += ubits(u3.x) * ubits(hw4.w); acc1 += ubits(u3.y) * ubits(hw4.w);
            }
        }
        if (!red_grp) zpart[kq * CP + cp] = make_float2(acc0, acc1);
        __syncthreads();    // bar1

        // ---- reduce + activations + xz prefetch (last k-group) ----
        if (red_grp) {
            float zx = z0.x + acc0;
            float zy = z0.y + acc1;
#pragma unroll
            for (int r = 0; r < NKG - 1; ++r) {
                const float2 p = zpart[r * CP + cp];
                zx += p.x; zy += p.y;
            }
            if (t + 1 < T_) z0 = *(const float2*)(xzb + (size_t)(t + 1) * GATES);
            float ax, ay;
            if (tanh_gate) { ax = ftanh(zx); ay = ftanh(zy); }
            else           { ax = fsig(zx);  ay = fsig(zy);  }
            *(float2*)&act_sh[c0] = make_float2(ax, ay);
        }
        __syncthreads();    // bar2

        // ---- cell update (wave 0, lanes < HB) ----
        float hnew = 0.f;
        if (tid < HB) {
            const float ig = act_sh[tid];
            const float fg = act_sh[HB + tid];
            const float gg = act_sh[2 * HB + tid];
            const float og = act_sh[3 * HB + tid];
            cst = fg * cst + ig * gg;
            hnew = og * ftanh(cst);
            if (out_last && t == T_ - 1) out_last[(size_t)b * HN + q * HB + tid] = hnew;
        }

        if (t < T_ - 1) {
            const int s = t & 1;
            unsigned int* hslot = hbuf + (size_t)s * B_ * HN + b * HN;
            const unsigned int tag = (unsigned int)(t + 1);

            // publish own h slice as tagged words (no fence, no vmcnt, no flag)
            if (tid < HB) {
                const unsigned int word = (tag << 16) | (unsigned int)f2h_bits(hnew);
                __hip_atomic_store(&hslot[q * HB + tid], word,
                                   __ATOMIC_RELAXED, __HIP_MEMORY_SCOPE_AGENT);
            }
            // hout store (off critical path, cached)
            if (hout && tid < HB)
                hout[((size_t)b * T_ + t) * HN + q * HB + tid] = hnew;

            // pull full h: load + retry until tags fresh (wave 0)
            if (tid < 64) {
                const unsigned long long* hq = (const unsigned long long*)hslot;
                if constexpr (F16) {
                    // lane: words 4*tid .. 4*tid+3 (two qwords)
                    unsigned long long vA = __hip_atomic_load(&hq[2 * tid],
                        __ATOMIC_RELAXED, __HIP_MEMORY_SCOPE_AGENT);
                    unsigned long long vB = __hip_atomic_load(&hq[2 * tid + 1],
                        __ATOMIC_RELAXED, __HIP_MEMORY_SCOPE_AGENT);
                    while (((vA >> 16) & 0xffffu) != tag || (vA >> 48) != tag)
                        vA = __hip_atomic_load(&hq[2 * tid],
                            __ATOMIC_RELAXED, __HIP_MEMORY_SCOPE_AGENT);
                    while (((vB >> 16) & 0xffffu) != tag || (vB >> 48) != tag)
                        vB = __hip_atomic_load(&hq[2 * tid + 1],
                            __ATOMIC_RELAXED, __HIP_MEMORY_SCOPE_AGENT);
                    hW[2 * tid] = (unsigned int)(vA & 0xffffu) |
                                  ((unsigned int)((vA >> 32) & 0xffffu) << 16);
                    hW[2 * tid + 1] = (unsigned int)(vB & 0xffffu) |
                                      ((unsigned int)((vB >> 32) & 0xffffu) << 16);
                } else {
                    // HN=128: lane: words 2*tid, 2*tid+1 (one qword)
                    unsigned long long v = __hip_atomic_load(&hq[tid],
                        __ATOMIC_RELAXED, __HIP_MEMORY_SCOPE_AGENT);
                    while (((v >> 16) & 0xffffu) != tag || (v >> 48) != tag)
                        v = __hip_atomic_load(&hq[tid],
                            __ATOMIC_RELAXED, __HIP_MEMORY_SCOPE_AGENT);
                    hW[2 * tid] = __builtin_bit_cast(unsigned int,
                        h2f_bits((unsigned int)v));
                    hW[2 * tid + 1] = __builtin_bit_cast(unsigned int,
                        h2f_bits((unsigned int)(v >> 32)));
                }
            }
            __syncthreads();    // bar3
        } else if (hout && tid < HB) {
            hout[((size_t)b * T_ + t) * HN + q * HB + tid] = hnew;
        }
    }
}

// ---------------------------------------------------------------------------
// Launch
// ---------------------------------------------------------------------------
extern "C" void kernel_launch(void* const* d_in, const int* in_sizes, int n_in,
                              void* d_out, int out_size, void* d_ws, size_t ws_size,
                              hipStream_t stream)
{
    const float* x  = (const float*)d_in[0];
    const float* W0 = (const float*)d_in[1];
    const float* U0 = (const float*)d_in[2];
    const float* b0 = (const float*)d_in[3];
    const float* W1 = (const float*)d_in[4];
    const float* U1 = (const float*)d_in[5];
    const float* b1 = (const float*)d_in[6];
    const float* W2 = (const float*)d_in[7];
    const float* U2 = (const float*)d_in[8];
    const float* b2 = (const float*)d_in[9];
    const float* m0 = (const float*)d_in[10];
    const float* m1 = (const float*)d_in[11];
    const float* m2 = (const float*)d_in[12];
    float* out = (float*)d_out;

    // workspace layout:
    //   xz    : 134217728 B   (64*512*1024 floats, reused by all 3 layers)
    //   h0    :  33554432 B
    //   h1    :  33554432 B
    //   hbuf  : 3 regions x 131072 B (2 x 64 x 256 tagged words per layer)
    char* ws = (char*)d_ws;
    float* xz = (float*)ws;
    float* h0 = (float*)(ws + 134217728);
    float* h1 = (float*)(ws + 134217728 + 33554432);
    unsigned int* hb0 = (unsigned int*)(ws + 134217728 + 2 * 33554432);
    unsigned int* hb1 = hb0 + 2 * B_ * 256;
    unsigned int* hb2 = hb1 + 2 * B_ * 256;

    const int M = B_ * T_;  // 32768

    // Layer 0
    gemm_mask_f16<<<dim3(1024 / 64, M / 64), 256, 0, stream>>>(x, W0, b0, m0, xz, M, 1024, 128);
    lstm_rec_v10<256, true><<<256, 1024, 0, stream>>>(xz, U0, h0, nullptr, hb0);

    // Layer 1
    gemm_mask_f16<<<dim3(1024 / 64, M / 64), 256, 0, stream>>>(h0, W1, b1, m1, xz, M, 1024, 256);
    lstm_rec_v10<256, true><<<256, 1024, 0, stream>>>(xz, U1, h1, nullptr, hb1);

    // Layer 2 (H=128, fp32 LDS compute, fp16 exchange), emit last h only
    gemm_mask_f16<<<dim3(512 / 64, M / 64), 256, 0, stream>>>(h1, W2, b2, m2, xz, M, 512, 256);
    lstm_rec_v10<128, false><<<256, 1024, 0, stream>>>(xz, U2, nullptr, out, hb2);
}